// Round 14
// baseline (1656.912 us; speedup 1.0000x reference)
//
#include <hip/hip_runtime.h>
#include <hip/hip_bf16.h>

// 2-layer LSTM (T=1024, B=512, IN=20, H1=128, H2=64) + head OUT=3.
// Only batch row 511 feeds the output => single-sequence scan.
//
// Pipeline:
//   A : xp1 = x[:,511,:] @ W_ih0^T + b0            (parallel)
//   P : pack W_hh0/W_hh1 f16 TRANSPOSED to global  (parallel, once)
//   B1: layer-1 scan — W via VMEM, h bcast via LDS (serial, 1 CU)
//   C1: xp2 = h1seq @ W_ih1^T + b1                 (parallel GEMM)
//   B2: layer-2 scan — same scheme                  (serial, 1 CU)
//   D : head                                        (parallel)
//
// Round-14: R11-R13 fit cycles/step = 116 + 7.25 * (LDS instrs) exactly ->
// the scan is LDS-ISSUE bound; VMEM W-stream and VALU hide beneath it.
// Cut LDS instrs: thread ownership goes (1 gate, 64-col half) -> (2 gates,
// 32-col quarter): h-broadcasts per thread 16 -> 8 (shared by both gates),
// W via 8 coalesced VMEM quads (unchanged bytes). Partials in stride-5 LDS.
// LDS slots ~304 -> ~210 => predicted ~680ns/step.
// Numerics unchanged: f16 W, exact hi/lo-f16 h (lo x4096).

#define T_STEPS 1024
#define BATCH   512
#define IN_F    20
#define H1_     128
#define H2_     64
#define OUT_F   3
#define G1_     (4*H1_)   // 512
#define G2_     (4*H2_)   // 256

typedef float f4 __attribute__((ext_vector_type(4)));
typedef float f2 __attribute__((ext_vector_type(2)));
typedef unsigned int u32;
typedef u32 u4 __attribute__((ext_vector_type(4)));
typedef _Float16 h2t __attribute__((ext_vector_type(2)));

__device__ __forceinline__ float sigmoidf_(float x) {
    return 1.0f / (1.0f + __expf(-x));
}
__device__ __forceinline__ float tanhf_(float x) {
    return 1.0f - 2.0f / (__expf(2.0f * x) + 1.0f);
}
__device__ __forceinline__ h2t as_h2(u32 v) {
    union { u32 u; h2t h; } c; c.u = v; return c.h;
}
__device__ __forceinline__ u32 pkh(float a, float b) {
    union { _Float16 h[2]; u32 u; } c;
    c.h[0] = (_Float16)a; c.h[1] = (_Float16)b; return c.u;
}
__device__ __forceinline__ float fdot2_(h2t a, h2t b, float c) {
#if __has_builtin(__builtin_amdgcn_fdot2)
    return __builtin_amdgcn_fdot2(a, b, c, false);
#else
    float d = c;
    asm("v_dot2_f32_f16 %0, %1, %2, %0" : "+v"(d) : "v"(a), "v"(b));
    return d;
#endif
}
__device__ __forceinline__ u4 packq(const float* p) {
    const f4 a = *(const f4*)p;
    const f4 b = *(const f4*)(p + 4);
    u4 pk;
    pk.x = pkh(a.x, a.y); pk.y = pkh(a.z, a.w);
    pk.z = pkh(b.x, b.y); pk.w = pkh(b.z, b.w);
    return pk;
}

#define LO_SCALE_INV 0.000244140625f   // 2^-12

// 8 fdot2 against one W quad into named accums (hi: A0/A1, lo: A2/A3)
#define DOTQ4(WQ, HH, HL, A0, A1, A2, A3)                                     \
    { A0 = fdot2_(as_h2((WQ).x), as_h2((HH).x), A0);                          \
      A1 = fdot2_(as_h2((WQ).y), as_h2((HH).y), A1);                          \
      A0 = fdot2_(as_h2((WQ).z), as_h2((HH).z), A0);                          \
      A1 = fdot2_(as_h2((WQ).w), as_h2((HH).w), A1);                          \
      A2 = fdot2_(as_h2((WQ).x), as_h2((HL).x), A2);                          \
      A3 = fdot2_(as_h2((WQ).y), as_h2((HL).y), A3);                          \
      A2 = fdot2_(as_h2((WQ).z), as_h2((HL).z), A2);                          \
      A3 = fdot2_(as_h2((WQ).w), as_h2((HL).w), A3); }

// ---------------- A: x-projection for batch row 511 --------------------------
__global__ void xproj_kernel(const float* __restrict__ x,
                             const float* __restrict__ W_ih0,
                             const float* __restrict__ b_ih0,
                             const float* __restrict__ b_hh0,
                             float* __restrict__ xp1)
{
    const int t = blockIdx.x;
    const int g = threadIdx.x;
    const float* xr = x + ((size_t)t * BATCH + (BATCH - 1)) * IN_F;
    const float* w  = W_ih0 + g * IN_F;
    float acc = b_ih0[g] + b_hh0[g];
#pragma unroll
    for (int i = 0; i < IN_F; ++i) acc = fmaf(xr[i], w[i], acc);
    xp1[t * G1_ + g] = acc;
}

// ---------------- P: pack W f16, transposed for coalesced scan reads ---------
// wpk1[q*1024 + v], v = qf*256 + r (qf=v>>8, r=v&255), q in [0,8):
//   gate g = 2r + (q>>2), cols qf*32 + (q&3)*8 .. +8   (128 KB)
// wpk2[q*1024 + v2], v2 = qf2*256 + g2 (qf2=v2>>8, g2=v2&255), q in [0,2):
//   = W_hh1[g2][qf2*16 + q*8 .. +8)  (32 KB)
__global__ void pack_kernel(const float* __restrict__ W_hh0,
                            const float* __restrict__ W_hh1,
                            u4* __restrict__ wpk1,
                            u4* __restrict__ wpk2)
{
    const int idx = blockIdx.x * blockDim.x + threadIdx.x;
    if (idx < 8192) {
        const int q = idx >> 10, v = idx & 1023;
        const int r = v & 255, qf = v >> 8;
        const int g = 2 * r + (q >> 2);
        wpk1[idx] = packq(W_hh0 + (size_t)g * H1_ + qf * 32 + (q & 3) * 8);
    } else if (idx < 8192 + 2048) {
        const int i2 = idx - 8192;
        const int q = i2 >> 10, v2 = i2 & 1023;
        const int g2 = v2 & 255, qf2 = v2 >> 8;
        wpk2[i2] = packq(W_hh1 + (size_t)g2 * H2_ + qf2 * 16 + q * 8);
    }
}

// ---------------- B1: layer-1 scan (serial, one block) -----------------------
// 1024 thr = 16 waves (4/SIMD). Thread (r=tid&255, qf=tid>>8) owns gates
// {2r, 2r+1} x cols [32qf, 32qf+32). h-broadcasts: 8 b128 (4 hi + 4 lo),
// shared by both gates. W: 8 coalesced VMEM quads. Partials sp1[g*5+qf].
__global__ __attribute__((amdgpu_flat_work_group_size(1024, 1024),
                          amdgpu_waves_per_eu(4, 4)))
void lstm1_kernel(const float* __restrict__ xp1,
                  const u4* __restrict__ wpk1,
                  float* __restrict__ h1seq)
{
    const int tid = threadIdx.x;
    const int r   = tid & 255;
    const int qf  = tid >> 8;          // wave-uniform quarter

    __shared__ u4    shhi[16];         // h_hi  f16[128]
    __shared__ u4    shlo[16];         // h_lo*4096 f16[128]
    __shared__ float sp1[G1_ * 5];     // partials [g*5+qf] (10 KB)

    if (tid < 16) { shhi[tid] = u4{0,0,0,0}; shlo[tid] = u4{0,0,0,0}; }
    float c1 = 0.0f;                   // owned by tid < 128
    __syncthreads();

    const u4* wb = wpk1 + tid;         // 8 loop-invariant, coalesced addresses
    f2 xp_cur = f2{0.f, 0.f};
    if (qf == 0) xp_cur = *(const f2*)(xp1 + 2 * r);

    for (int t = 0; t < T_STEPS; ++t) {
        f2 xp_next = f2{0.f, 0.f};
        if (qf == 0) {
            const int tn = (t + 1 < T_STEPS) ? (t + 1) : (T_STEPS - 1);
            xp_next = *(const f2*)(xp1 + (size_t)tn * G1_ + 2 * r);
        }
        // W quads: q=0..3 -> gate 2r, q=4..7 -> gate 2r+1 (VMEM pipe)
        const u4 wa0 = wb[0 * 1024], wa1 = wb[1 * 1024];
        const u4 wa2 = wb[2 * 1024], wa3 = wb[3 * 1024];
        const u4 wb0 = wb[4 * 1024], wb1 = wb[5 * 1024];
        const u4 wb2 = wb[6 * 1024], wb3 = wb[7 * 1024];
        // h quads (LDS, uniform-broadcast): shared by both gates
        const u4 hh0 = shhi[qf * 4 + 0], hl0 = shlo[qf * 4 + 0];
        const u4 hh1 = shhi[qf * 4 + 1], hl1 = shlo[qf * 4 + 1];
        const u4 hh2 = shhi[qf * 4 + 2], hl2 = shlo[qf * 4 + 2];
        const u4 hh3 = shhi[qf * 4 + 3], hl3 = shlo[qf * 4 + 3];

        float a0 = 0.f, a1 = 0.f, a2 = 0.f, a3 = 0.f;   // gate 2r
        float b0 = 0.f, b1 = 0.f, b2 = 0.f, b3 = 0.f;   // gate 2r+1
        DOTQ4(wa0, hh0, hl0, a0, a1, a2, a3);
        DOTQ4(wa1, hh1, hl1, a0, a1, a2, a3);
        DOTQ4(wa2, hh2, hl2, a0, a1, a2, a3);
        DOTQ4(wa3, hh3, hl3, a0, a1, a2, a3);
        DOTQ4(wb0, hh0, hl0, b0, b1, b2, b3);
        DOTQ4(wb1, hh1, hl1, b0, b1, b2, b3);
        DOTQ4(wb2, hh2, hl2, b0, b1, b2, b3);
        DOTQ4(wb3, hh3, hl3, b0, b1, b2, b3);

        sp1[(2 * r)     * 5 + qf] = ((a0 + a1) + LO_SCALE_INV * (a2 + a3)) + xp_cur.x;
        sp1[(2 * r + 1) * 5 + qf] = ((b0 + b1) + LO_SCALE_INV * (b2 + b3)) + xp_cur.y;
        __syncthreads();   // partials ready (also orders prev h stores)

        // ---- pointwise (tid<128): combine 4 quarters, activate, publish h --
        if (tid < H1_) {
            const int j = tid;
            const float* s0 = sp1 + j * 5;
            const float* s1 = sp1 + (H1_ + j) * 5;
            const float* s2 = sp1 + (2 * H1_ + j) * 5;
            const float* s3 = sp1 + (3 * H1_ + j) * 5;
            const float vi = (s0[0] + s0[1]) + (s0[2] + s0[3]);
            const float vf = (s1[0] + s1[1]) + (s1[2] + s1[3]);
            const float vg = (s2[0] + s2[1]) + (s2[2] + s2[3]);
            const float vo = (s3[0] + s3[1]) + (s3[2] + s3[3]);
            c1 = fmaf(sigmoidf_(vf), c1, sigmoidf_(vi) * tanhf_(vg));
            const float h = sigmoidf_(vo) * tanhf_(c1);
            const _Float16 hh16 = (_Float16)h;
            const float hrem = (h - (float)hh16) * 4096.0f;
            ((_Float16*)shhi)[j] = hh16;
            ((_Float16*)shlo)[j] = (_Float16)hrem;
            h1seq[(size_t)t * H1_ + j] = h;   // fire-and-forget (f32 state)
        }
        __syncthreads();   // h f16 arrays ready
        xp_cur = xp_next;
    }
}

// ---------------- C1: xp2 = h1seq @ W_ih1^T + (b_ih1 + b_hh1) ---------------
__global__ void xproj2_kernel(const float* __restrict__ h1seq,
                              const float* __restrict__ W_ih1,
                              const float* __restrict__ b_ih1,
                              const float* __restrict__ b_hh1,
                              float* __restrict__ xp2)
{
    const int t = blockIdx.x;
    const int g = threadIdx.x;
    __shared__ f4 sh[H1_ / 4];
    if (g < H1_ / 4) sh[g] = ((const f4*)(h1seq + (size_t)t * H1_))[g];
    __syncthreads();
    const f4* w = (const f4*)(W_ih1 + (size_t)g * H1_);
    float ax = 0.f, ay = 0.f, az = 0.f, aw = 0.f;
#pragma unroll
    for (int k = 0; k < H1_ / 4; ++k) {
        const f4 h4 = sh[k]; const f4 w4 = w[k];
        ax = fmaf(w4.x, h4.x, ax); ay = fmaf(w4.y, h4.y, ay);
        az = fmaf(w4.z, h4.z, az); aw = fmaf(w4.w, h4.w, aw);
    }
    xp2[(size_t)t * G2_ + g] = ((ax + ay) + (az + aw)) + b_ih1[g] + b_hh1[g];
}

// ---------------- B2: layer-2 scan (serial, one block) -----------------------
// 1024 thr = 16 waves (4/SIMD). Thread (g2=tid&255, qf=tid>>8) owns 16 weights
// (quarter row) from wpk2 (coalesced VMEM). LDS: 4 bcast/thread + sp2[g2*4+qf].
__global__ __attribute__((amdgpu_flat_work_group_size(1024, 1024),
                          amdgpu_waves_per_eu(4, 4)))
void lstm2_kernel(const float* __restrict__ xp2,
                  const u4* __restrict__ wpk2,
                  float* __restrict__ h2seq)
{
    const int tid = threadIdx.x;
    const int g2  = tid & 255;
    const int qf  = tid >> 8;          // wave-uniform quarter

    __shared__ u4    shhi[8];          // h_hi  f16[64]
    __shared__ u4    shlo[8];          // h_lo*4096 f16[64]
    __shared__ float sp2[1024];        // partials [g2*4+qf] (4 KB)

    if (tid < 8) { shhi[tid] = u4{0,0,0,0}; shlo[tid] = u4{0,0,0,0}; }
    float c2 = 0.0f;                   // owned by tid < 64
    __syncthreads();

    const u4* wb = wpk2 + tid;         // 2 loop-invariant, coalesced addresses
    float xp_cur = (qf == 0) ? xp2[g2] : 0.0f;

    for (int t = 0; t < T_STEPS; ++t) {
        float xp_next = 0.0f;
        if (qf == 0) {
            const int tn = (t + 1 < T_STEPS) ? (t + 1) : (T_STEPS - 1);
            xp_next = xp2[(size_t)tn * G2_ + g2];
        }
        const u4 w0_ = wb[0], w1_ = wb[1024];
        const u4 hh0 = shhi[qf * 2 + 0], hl0 = shlo[qf * 2 + 0];
        const u4 hh1 = shhi[qf * 2 + 1], hl1 = shlo[qf * 2 + 1];

        float a0 = 0.f, a1 = 0.f, a2 = 0.f, a3 = 0.f;
        DOTQ4(w0_, hh0, hl0, a0, a1, a2, a3);
        DOTQ4(w1_, hh1, hl1, a0, a1, a2, a3);

        sp2[g2 * 4 + qf] = ((a0 + a1) + LO_SCALE_INV * (a2 + a3)) + xp_cur;
        __syncthreads();   // partials ready (also orders prev h stores)

        // ---- pointwise (tid<64): combine quarters, activate, publish h -----
        if (tid < H2_) {
            const f4 pi = ((const f4*)sp2)[tid];
            const f4 pf = ((const f4*)sp2)[H2_ + tid];
            const f4 pg = ((const f4*)sp2)[2 * H2_ + tid];
            const f4 po = ((const f4*)sp2)[3 * H2_ + tid];
            const float vi = (pi.x + pi.y) + (pi.z + pi.w);
            const float vf = (pf.x + pf.y) + (pf.z + pf.w);
            const float vg = (pg.x + pg.y) + (pg.z + pg.w);
            const float vo = (po.x + po.y) + (po.z + po.w);
            c2 = fmaf(sigmoidf_(vf), c2, sigmoidf_(vi) * tanhf_(vg));
            const float h = sigmoidf_(vo) * tanhf_(c2);
            const _Float16 hh16 = (_Float16)h;
            const float hrem = (h - (float)hh16) * 4096.0f;
            ((_Float16*)shhi)[tid] = hh16;
            ((_Float16*)shlo)[tid] = (_Float16)hrem;
            h2seq[(size_t)t * H2_ + tid] = h;
        }
        __syncthreads();   // h f16 arrays ready
        xp_cur = xp_next;
    }
}

// ---------------- D: head out[t,o] = relu(h2[t]) . W_d[o] + b_d --------------
__global__ void head_kernel(const float* __restrict__ h2seq,
                            const float* __restrict__ W_d,
                            const float* __restrict__ b_d,
                            float* __restrict__ out)
{
    const int idx = blockIdx.x * blockDim.x + threadIdx.x;
    if (idx >= T_STEPS * OUT_F) return;
    const int t = idx / OUT_F;
    const int o = idx - t * OUT_F;
    const float* hr = h2seq + (size_t)t * H2_;
    const float* w  = W_d + o * H2_;
    float acc = b_d[o];
#pragma unroll
    for (int j = 0; j < H2_; ++j) acc = fmaf(fmaxf(hr[j], 0.0f), w[j], acc);
    out[idx] = acc;
}

extern "C" void kernel_launch(void* const* d_in, const int* in_sizes, int n_in,
                              void* d_out, int out_size, void* d_ws, size_t ws_size,
                              hipStream_t stream) {
    const float* x     = (const float*)d_in[0];
    const float* W_ih0 = (const float*)d_in[1];
    const float* W_hh0 = (const float*)d_in[2];
    const float* b_ih0 = (const float*)d_in[3];
    const float* b_hh0 = (const float*)d_in[4];
    const float* W_ih1 = (const float*)d_in[5];
    const float* W_hh1 = (const float*)d_in[6];
    const float* b_ih1 = (const float*)d_in[7];
    const float* b_hh1 = (const float*)d_in[8];
    const float* W_d   = (const float*)d_in[9];
    const float* b_d   = (const float*)d_in[10];

    float* out   = (float*)d_out;
    float* xp1   = (float*)d_ws;                         // [1024][512] = 2 MB
    float* h1seq = xp1 + (size_t)T_STEPS * G1_;          // [1024][128] = 512 KB
    float* h2seq = h1seq + (size_t)T_STEPS * H1_;        // [1024][64]  = 256 KB
    u4*    wpk1  = (u4*)(h2seq + (size_t)T_STEPS * H2_); // 8192*16B = 128 KB
    u4*    wpk2  = wpk1 + 8192;                          // 2048*16B =  32 KB
    float* xp2   = xp1;                                  // overlay (xp1 dead after B1)

    hipLaunchKernelGGL(xproj_kernel, dim3(T_STEPS), dim3(G1_), 0, stream,
                       x, W_ih0, b_ih0, b_hh0, xp1);
    hipLaunchKernelGGL(pack_kernel, dim3(40), dim3(256), 0, stream,
                       W_hh0, W_hh1, wpk1, wpk2);
    hipLaunchKernelGGL(lstm1_kernel, dim3(1), dim3(1024), 0, stream,
                       xp1, wpk1, h1seq);
    hipLaunchKernelGGL(xproj2_kernel, dim3(T_STEPS), dim3(G2_), 0, stream,
                       h1seq, W_ih1, b_ih1, b_hh1, xp2);
    hipLaunchKernelGGL(lstm2_kernel, dim3(1), dim3(1024), 0, stream,
                       xp2, wpk2, h2seq);
    hipLaunchKernelGGL(head_kernel, dim3((T_STEPS * OUT_F + 255) / 256), dim3(256),
                       0, stream, h2seq, W_d, b_d, out);
}